// Round 3
// baseline (1682.160 us; speedup 1.0000x reference)
//
#include <hip/hip_runtime.h>
#include <math.h>

#define B_ 32
#define T_ 128
#define D_ 768
#define A_ 512
#define R_ 128
#define L_ 50

// ---------------------------------------------------------------------------
// Fused projection GEMM: HA/DA/HL/DL = ELU(X @ W + b) in one launch.
// ---------------------------------------------------------------------------
__global__ __launch_bounds__(256)
void proj_gemm_k(const float* __restrict__ X,
                 const float* __restrict__ Wha, const float* __restrict__ bha,
                 const float* __restrict__ Wda, const float* __restrict__ bda,
                 const float* __restrict__ Whl, const float* __restrict__ bhl,
                 const float* __restrict__ Wdl, const float* __restrict__ bdl,
                 float* __restrict__ HA, float* __restrict__ DA,
                 float* __restrict__ HL, float* __restrict__ DL)
{
    __shared__ float As[16][68];
    __shared__ float Bs[16][132];
    const int bx = blockIdx.x;
    const float *W, *bias; float* C; int ld, ncol;
    if (bx < 4)      { W = Wha; bias = bha; C = HA; ld = 512; ncol = bx * 128; }
    else if (bx < 8) { W = Wda; bias = bda; C = DA; ld = 512; ncol = (bx - 4) * 128; }
    else if (bx == 8){ W = Whl; bias = bhl; C = HL; ld = 128; ncol = 0; }
    else             { W = Wdl; bias = bdl; C = DL; ld = 128; ncol = 0; }
    const int m0 = blockIdx.y * 64;
    const int tid = threadIdx.x;
    const int tx = tid & 15, ry = tid >> 4;
    float acc[4][8] = {};
    for (int k0 = 0; k0 < 768; k0 += 16) {
        {
            int row = tid >> 2, kb = (tid & 3) * 4;
            float4 a = *(const float4*)&X[(size_t)(m0 + row) * 768 + k0 + kb];
            As[kb + 0][row] = a.x; As[kb + 1][row] = a.y;
            As[kb + 2][row] = a.z; As[kb + 3][row] = a.w;
        }
        {
            int kk = tid >> 4, c0 = (tid & 15) * 4;
            const float* Bp = &W[(size_t)(k0 + kk) * ld + ncol + c0];
            *(float4*)&Bs[kk][c0] = *(const float4*)&Bp[0];
            *(float4*)&Bs[kk][c0 + 64] = *(const float4*)&Bp[64];
        }
        __syncthreads();
#pragma unroll
        for (int kk = 0; kk < 16; ++kk) {
            float4 a4 = *(const float4*)&As[kk][ry * 4];
            float4 b0 = *(const float4*)&Bs[kk][tx * 4];
            float4 b1 = *(const float4*)&Bs[kk][tx * 4 + 64];
            float av[4] = { a4.x, a4.y, a4.z, a4.w };
            float bv[8] = { b0.x, b0.y, b0.z, b0.w, b1.x, b1.y, b1.z, b1.w };
#pragma unroll
            for (int i = 0; i < 4; ++i)
#pragma unroll
                for (int j = 0; j < 8; ++j)
                    acc[i][j] += av[i] * bv[j];
        }
        __syncthreads();
    }
    float bv0[8];
    {
        float4 q0 = *(const float4*)&bias[ncol + tx * 4];
        float4 q1 = *(const float4*)&bias[ncol + tx * 4 + 64];
        bv0[0] = q0.x; bv0[1] = q0.y; bv0[2] = q0.z; bv0[3] = q0.w;
        bv0[4] = q1.x; bv0[5] = q1.y; bv0[6] = q1.z; bv0[7] = q1.w;
    }
#pragma unroll
    for (int i = 0; i < 4; ++i) {
        int m = m0 + ry * 4 + i;
        size_t base = (size_t)m * ld + ncol;
        float o[8];
#pragma unroll
        for (int j = 0; j < 8; ++j) {
            float v = acc[i][j] + bv0[j];
            o[j] = v > 0.0f ? v : expm1f(v);
        }
        float4 s0 = { o[0], o[1], o[2], o[3] };
        float4 s1 = { o[4], o[5], o[6], o[7] };
        *(float4*)&C[base + tx * 4] = s0;
        *(float4*)&C[base + tx * 4 + 64] = s1;
    }
}

// ---------------------------------------------------------------------------
// fp32 GEMM, tile 64x128, 256 threads, 4x8 acc/thread, b128 LDS reads.
// ---------------------------------------------------------------------------
__global__ __launch_bounds__(256)
void gemm_k(const float* __restrict__ A, const float* __restrict__ B,
            const float* __restrict__ bias, float* __restrict__ C,
            int K, int lda, int ldb, int ldc,
            long long sA, long long sB, long long sC, long long c_outer, int flags)
{
    __shared__ float As[16][68];
    __shared__ float Bs[16][132];
    A += (size_t)blockIdx.z * sA;
    B += (size_t)blockIdx.z * sB;
    C += (size_t)blockIdx.z * sC;
    const int m0 = blockIdx.y * 64, n0 = blockIdx.x * 128;
    const int tid = threadIdx.x;
    const int tx = tid & 15, ry = tid >> 4;
    float acc[4][8] = {};
    for (int k0 = 0; k0 < K; k0 += 16) {
        {
            int row = tid >> 2, kb = (tid & 3) * 4;
            float4 a = *(const float4*)&A[(size_t)(m0 + row) * lda + k0 + kb];
            As[kb + 0][row] = a.x; As[kb + 1][row] = a.y;
            As[kb + 2][row] = a.z; As[kb + 3][row] = a.w;
        }
        if (!(flags & 4)) {
            int kk = tid >> 4, c0 = (tid & 15) * 4;
            const float* Bp = &B[(size_t)(k0 + kk) * ldb + n0 + c0];
            *(float4*)&Bs[kk][c0] = *(const float4*)&Bp[0];
            *(float4*)&Bs[kk][c0 + 64] = *(const float4*)&Bp[64];
        } else {
            int col = tid >> 1, kb = (tid & 1) * 8;
            const float* Bp = &B[(size_t)(n0 + col) * ldb + k0 + kb];
            float4 b0 = *(const float4*)&Bp[0];
            float4 b1 = *(const float4*)&Bp[4];
            Bs[kb + 0][col] = b0.x; Bs[kb + 1][col] = b0.y;
            Bs[kb + 2][col] = b0.z; Bs[kb + 3][col] = b0.w;
            Bs[kb + 4][col] = b1.x; Bs[kb + 5][col] = b1.y;
            Bs[kb + 6][col] = b1.z; Bs[kb + 7][col] = b1.w;
        }
        __syncthreads();
#pragma unroll
        for (int kk = 0; kk < 16; ++kk) {
            float4 a4 = *(const float4*)&As[kk][ry * 4];
            float4 b0 = *(const float4*)&Bs[kk][tx * 4];
            float4 b1 = *(const float4*)&Bs[kk][tx * 4 + 64];
            float av[4] = { a4.x, a4.y, a4.z, a4.w };
            float bv[8] = { b0.x, b0.y, b0.z, b0.w, b1.x, b1.y, b1.z, b1.w };
#pragma unroll
            for (int i = 0; i < 4; ++i)
#pragma unroll
                for (int j = 0; j < 8; ++j)
                    acc[i][j] += av[i] * bv[j];
        }
        __syncthreads();
    }
    float bv0[8] = {};
    if (flags & 1) {
        float4 q0 = *(const float4*)&bias[n0 + tx * 4];
        float4 q1 = *(const float4*)&bias[n0 + tx * 4 + 64];
        bv0[0] = q0.x; bv0[1] = q0.y; bv0[2] = q0.z; bv0[3] = q0.w;
        bv0[4] = q1.x; bv0[5] = q1.y; bv0[6] = q1.z; bv0[7] = q1.w;
    }
#pragma unroll
    for (int i = 0; i < 4; ++i) {
        int m = m0 + ry * 4 + i;
        size_t base = (size_t)(m >> 7) * c_outer + (size_t)(m & 127) * ldc + n0;
        float o[8];
#pragma unroll
        for (int j = 0; j < 8; ++j) {
            float v = acc[i][j] + bv0[j];
            if (flags & 2) v = v > 0.0f ? v : expm1f(v);
            o[j] = v;
        }
        float4 s0 = { o[0], o[1], o[2], o[3] };
        float4 s1 = { o[4], o[5], o[6], o[7] };
        *(float4*)&C[base + tx * 4] = s0;
        *(float4*)&C[base + tx * 4 + 64] = s1;
    }
}

// 128x128 per-batch transpose: DLt[b][s][j] = DL[b][j][s]
__global__ __launch_bounds__(256)
void transpose_k(const float* __restrict__ in, float* __restrict__ out)
{
    __shared__ float tile[32][33];
    int b = blockIdx.z;
    int bx = blockIdx.x, by = blockIdx.y;
    int tx = threadIdx.x, ty = threadIdx.y; // (32,8)
    const float* src = in + (size_t)b * T_ * R_;
    float* dst = out + (size_t)b * T_ * R_;
#pragma unroll
    for (int r = 0; r < 4; ++r)
        tile[ty + 8 * r][tx] = src[(size_t)(by * 32 + ty + 8 * r) * 128 + bx * 32 + tx];
    __syncthreads();
#pragma unroll
    for (int r = 0; r < 4; ++r)
        dst[(size_t)(bx * 32 + ty + 8 * r) * 128 + by * 32 + tx] = tile[tx][ty + 8 * r];
}

// log_softmax over dim 1 (i) of (32,128,128), in place. thread = column j.
__global__ __launch_bounds__(128)
void arc_logsoftmax_k(float* __restrict__ arc)
{
    int b = blockIdx.x, j = threadIdx.x;
    float* base = arc + (size_t)b * T_ * T_ + j;
    float m = -INFINITY;
    for (int i = 0; i < T_; ++i) m = fmaxf(m, base[(size_t)i * T_]);
    float s = 0.0f;
    for (int i = 0; i < T_; ++i) s += expf(base[(size_t)i * T_] - m);
    float ls = m + logf(s);
    for (int i = 0; i < T_; ++i) base[(size_t)i * T_] -= ls;
}

// In-place per-(b,l): E_slice <- (E_slice[i][s]) @ DLt[b]^( [s][j] )
__global__ __launch_bounds__(256)
void lab_inplace_k(float* __restrict__ E, const float* __restrict__ dlt)
{
    __shared__ __align__(16) float As[T_ * R_]; // 64 KB: [i][s]
    int l = blockIdx.x, b = blockIdx.y;
    float* base = E + ((size_t)b * L_ + l) * T_ * T_;
    int tid = threadIdx.x;
#pragma unroll
    for (int it = 0; it < 16; ++it) {
        int idx = (it * 256 + tid) * 4;
        *(float4*)&As[idx] = *(const float4*)&base[idx];
    }
    __syncthreads();
    int tx = tid & 15, ty = tid >> 4;
    int j0 = tx * 8, i0 = ty * 8;
    const float* dl = dlt + (size_t)b * T_ * R_;
    float acc[8][8] = {};
    for (int s0 = 0; s0 < R_; s0 += 4) {
        float a[8][4], bb[4][8];
#pragma unroll
        for (int ii = 0; ii < 8; ++ii) {
            float4 v = *(const float4*)&As[(i0 + ii) * R_ + s0];
            a[ii][0] = v.x; a[ii][1] = v.y; a[ii][2] = v.z; a[ii][3] = v.w;
        }
#pragma unroll
        for (int ss = 0; ss < 4; ++ss) {
            float4 x = *(const float4*)&dl[(size_t)(s0 + ss) * T_ + j0];
            float4 y = *(const float4*)&dl[(size_t)(s0 + ss) * T_ + j0 + 4];
            bb[ss][0] = x.x; bb[ss][1] = x.y; bb[ss][2] = x.z; bb[ss][3] = x.w;
            bb[ss][4] = y.x; bb[ss][5] = y.y; bb[ss][6] = y.z; bb[ss][7] = y.w;
        }
#pragma unroll
        for (int ii = 0; ii < 8; ++ii)
#pragma unroll
            for (int jj = 0; jj < 8; ++jj)
#pragma unroll
                for (int ss = 0; ss < 4; ++ss)
                    acc[ii][jj] += a[ii][ss] * bb[ss][jj];
    }
#pragma unroll
    for (int ii = 0; ii < 8; ++ii) {
        float4 o0 = { acc[ii][0], acc[ii][1], acc[ii][2], acc[ii][3] };
        float4 o1 = { acc[ii][4], acc[ii][5], acc[ii][6], acc[ii][7] };
        *(float4*)&base[(size_t)(i0 + ii) * T_ + j0] = o0;
        *(float4*)&base[(size_t)(i0 + ii) * T_ + j0 + 4] = o1;
    }
}

// energy combine + fused score/labmax for MST.
__global__ __launch_bounds__(256)
void energy_combine_k(float* __restrict__ E, const float* __restrict__ narc,
                      float* __restrict__ score_g, unsigned char* __restrict__ labmax_g)
{
    int g = blockIdx.x * 256 + threadIdx.x; // 0..524287
    int b = g >> 14;
    int ij = g & 16383;
    float* base = E + (size_t)b * L_ * T_ * T_ + ij;
    float v[L_];
    float m = -INFINITY;
    int am = 0;
#pragma unroll
    for (int l = 0; l < L_; ++l) {
        v[l] = base[(size_t)l * T_ * T_];
        if (v[l] > m) { m = v[l]; am = l; }
    }
    float s = 0.0f;
#pragma unroll
    for (int l = 0; l < L_; ++l) s += expf(v[l] - m);
    float ls = m + logf(s);
    float na = narc[(size_t)b * T_ * T_ + ij];
#pragma unroll
    for (int l = 0; l < L_; ++l) base[(size_t)l * T_ * T_] = expf(na + v[l] - ls);
    int i = ij >> 7, j = ij & 127;
    score_g[(size_t)b * 16384 + ij] = (i == j) ? 0.0f : expf(na + m - ls);
    labmax_g[(size_t)b * 16384 + ij] = (unsigned char)am;
}

// ---------------------------------------------------------------------------
// Chu-Liu-Edmonds MST decode. One block per batch element; main loop on wave 0
// (64 lanes x 2 nodes), zero barriers, all state in LDS.
// r5: MULTI-CYCLE contraction per pass (Boruvka-style):
//  - doubling computes a(n) = 128-step ancestor and m(n) = path-min.
//    For on-cycle n, m(n) = min node of its cycle = canonical cycle id = rep.
//  - ALL disjoint cycles contracted simultaneously each pass:
//    bucket members by cid (LDS atomics + packed wave scan for offsets),
//    stage 1 writes out-edges s[n][rep_c] from original rows, stage 2 writes
//    in-edges s[rep_c][n] reading post-stage-1 values (this ordering
//    reproduces sequential contraction's rep<->rep scores exactly).
//  - parents: incremental (p -> cid(p) if p on a cycle); surviving reps get a
//    full active-column rescan (root-first strict-max, matching reference).
//  - unwind: all cycles of a level resolved in parallel (one lane-walk per
//    cycle; exactly one key candidate exists per cycle).
//  - stride-129 padding on score/oin/oout: column reads/writes conflict-free.
// Ties (exact float equality) may resolve differently from the reference;
// MST unique otherwise. Waves 1-3 wait at the exit barrier.
// ---------------------------------------------------------------------------
__global__ __launch_bounds__(256)
void mst_k(const float* __restrict__ score_g, const unsigned char* __restrict__ labmax_g,
           float* __restrict__ heads, float* __restrict__ tags)
{
    const int b = blockIdx.x, t = threadIdx.x;
    __shared__ float score[128 * 129];        // 66 KB, stride 129
    __shared__ unsigned char oin[128 * 129];  // 16.1 KB
    __shared__ unsigned char oout[128 * 129]; // 16.1 KB
    __shared__ unsigned char pstL[128 * 128]; // 16 KB: old parents per level
    __shared__ unsigned char kynL[128 * 128]; // 16 KB: key cand (old r) per level
    __shared__ int parents[128];
    __shared__ int fe[128]; // -2 = absent; -1 = root marker
    __shared__ float pmx[128];
    __shared__ int pp[128];
    __shared__ float cwacc[128];
    __shared__ int cnt[128];
    __shared__ int offarr[128];
    __shared__ float Lsub[128];
    __shared__ unsigned char Lnode[128], Lcid[128];
    __shared__ unsigned char cidarr[128], actarr[128], oncyc[128];

    volatile float* vscore = score;
    volatile unsigned char* voin = oin;
    volatile unsigned char* voout = oout;
    volatile unsigned char* vpst = pstL;
    volatile unsigned char* vkyn = kynL;
    volatile int* vfe = fe;
    volatile float* vcw = cwacc;
    volatile int* vcnt = cnt;
    volatile int* voff = offarr;
    volatile float* vLs = Lsub;
    volatile unsigned char* vLn = Lnode;
    volatile unsigned char* vLc = Lcid;
    volatile unsigned char* vcid = cidarr;
    volatile unsigned char* vact = actarr;
    volatile unsigned char* vonc = oncyc;

    // ---- phase 0: stage score (padded), init oin/oout/fe/act ----
    {
        const float4* src = (const float4*)(score_g + (size_t)b * 16384);
        for (int i = t; i < 4096; i += 256) {
            float4 v = src[i];
            int r = i >> 5, c = (i & 31) * 4;
            float* d = &score[r * 129 + c];
            d[0] = v.x; d[1] = v.y; d[2] = v.z; d[3] = v.w;
        }
    }
    for (int i = t; i < 16384; i += 256) {
        int r = i >> 7, c = i & 127;
        oin[r * 129 + c] = (unsigned char)r;
        oout[r * 129 + c] = (unsigned char)c;
    }
    if (t < 128) { fe[t] = -2; oncyc[t] = 0; actarr[t] = 1; }
    __syncthreads();
    if (t < 128) score[t * 129 + t] = -INFINITY; // diag never read elsewhere
    __syncthreads();
    // ---- initial full parent scan (split across 256 threads) ----
    float mxl = 0.0f; int pl = 0;
    if (t >= 128) {
        int col = t - 128;
        float mx = -INFINITY; int pu = 64;
        if (col != 0) {
            mx = score[64 * 129 + col];
#pragma unroll 16
            for (int n2 = 65; n2 < 128; ++n2) {
                float sc = score[n2 * 129 + col];
                if (sc > mx) { mx = sc; pu = n2; }
            }
        }
        pmx[col] = mx; pp[col] = pu;
    } else if (t != 0) {
        mxl = score[t]; pl = 0; // row 0 initial (root candidate)
#pragma unroll 16
        for (int n2 = 1; n2 < 64; ++n2) {
            float sc = score[n2 * 129 + t];
            if (sc > mxl) { mxl = sc; pl = n2; }
        }
    }
    __syncthreads();
    if (t == 0) parents[0] = -1;
    else if (t < 128) parents[t] = (pmx[t] > mxl) ? pp[t] : pl;
    __syncthreads(); // ---- barrier A: wave 0 takes over ----

    if (t < 64) {
        const int n0 = t, n1 = t + 64;
        int p0 = parents[n0], p1 = parents[n1];
        int c0 = 1, c1 = 1;       // active flags
        int r0 = n0, r1 = n1;     // rep_of (group representative) mirrors
        int lev = 0, nact = 128;
        for (;;) {
            // --- doubling: a = 2^r-step ancestor, m = path-min ---
            int rounds = 32 - __clz(nact - 1);
            int a0 = (n0 == 0 || !c0) ? 0 : p0;
            int a1 = (!c1) ? 0 : p1;
            int m0 = n0, m1 = n1;
            for (int s = 0; s < rounds; ++s) {
                int pk0 = (a0 << 7) | m0;
                int pk1 = (a1 << 7) | m1;
                int s0l = a0 & 63, s1l = a1 & 63;
                int q00 = __shfl(pk0, s0l, 64);
                int q01 = __shfl(pk1, s0l, 64);
                int q10 = __shfl(pk0, s1l, 64);
                int q11 = __shfl(pk1, s1l, 64);
                int g0 = (a0 & 64) ? q01 : q00;
                int g1 = (a1 & 64) ? q11 : q10;
                a0 = g0 >> 7; int gm0 = g0 & 127; m0 = gm0 < m0 ? gm0 : m0;
                a1 = g1 >> 7; int gm1 = g1 & 127; m1 = gm1 < m1 ? gm1 : m1;
            }
            int pred0 = (n0 >= 1) && c0 && (a0 != 0);
            int pred1 = c1 && (a1 != 0);
            unsigned long long bal0 = __ballot(pred0);
            unsigned long long bal1 = __ballot(pred1);
            if (bal0 == 0ull && bal1 == 0ull) {
                // base case: no cycles — emit final edges for active nodes
                if (n0 == 0) vfe[0] = -1;
                else if (c0) vfe[voout[p0 * 129 + n0]] = voin[p0 * 129 + n0];
                if (c1) vfe[voout[p1 * 129 + n1]] = voin[p1 * 129 + n1];
                __threadfence_block();
                break;
            }
            // --- mark all cycle nodes; clear per-pass accumulators ---
            unsigned char ep = (unsigned char)(lev + 1);
            if (pred0) vonc[a0] = ep;
            if (pred1) vonc[a1] = ep;
            vcnt[n0] = 0; vcnt[n1] = 0;
            vcw[n0] = 0.0f; vcw[n1] = 0.0f;
            __threadfence_block(); // fence A
            int onc0 = c0 && (vonc[n0] == ep);
            int onc1 = c1 && (vonc[n1] == ep);
            int cid0 = m0, cid1 = m1; // valid only when onc
            vcid[n0] = onc0 ? (unsigned char)cid0 : 0xFF;
            vcid[n1] = onc1 ? (unsigned char)cid1 : 0xFF;
            float sub0 = 0.0f, sub1 = 0.0f;
            int rk0 = 0, rk1 = 0;
            if (onc0) { sub0 = vscore[p0 * 129 + n0]; rk0 = atomicAdd(&cnt[cid0], 1); atomicAdd(&cwacc[cid0], sub0); }
            if (onc1) { sub1 = vscore[p1 * 129 + n1]; rk1 = atomicAdd(&cnt[cid1], 1); atomicAdd(&cwacc[cid1], sub1); }
            __threadfence_block(); // fence B
            // --- packed wave scan of cnt -> segment offsets (node-id order) ---
            int x0 = vcnt[n0], x1 = vcnt[n1];
            int v = (x0 & 0xFFFF) | (x1 << 16);
            for (int off = 1; off < 64; off <<= 1) {
                int srcl = t >= off ? t - off : 0;
                int u = __shfl(v, srcl, 64);
                v += (t >= off) ? u : 0;
            }
            int tot = __shfl(v, 63, 64);
            int Mtot = (tot & 0xFFFF) + (tot >> 16);
            voff[n0] = (v & 0xFFFF) - x0;
            voff[n1] = (tot & 0xFFFF) + ((v >> 16) & 0xFFFF) - x1;
            __threadfence_block(); // fence C
            if (onc0) { int sl = voff[cid0] + rk0; vLn[sl] = (unsigned char)n0; vLc[sl] = (unsigned char)cid0; vLs[sl] = sub0; }
            if (onc1) { int sl = voff[cid1] + rk1; vLn[sl] = (unsigned char)n1; vLc[sl] = (unsigned char)cid1; vLs[sl] = sub1; }
            // --- save level state ---
            vpst[lev * 128 + n0] = (unsigned char)p0;
            vpst[lev * 128 + n1] = (unsigned char)p1;
            int rc0 = vcid[r0], rc1 = vcid[r1];
            vkyn[lev * 128 + n0] = (rc0 != 0xFF) ? (unsigned char)r0 : 0xFF;
            vkyn[lev * 128 + n1] = (rc1 != 0xFF) ? (unsigned char)r1 : 0xFF;
            if (rc0 != 0xFF) r0 = rc0;
            if (rc1 != 0xFF) r1 = rc1;
            __threadfence_block(); // fence D
            int cidn0 = onc0 ? cid0 : 0xFF;
            int cidn1 = onc1 ? cid1 : 0xFF;
            // --- stage 1: out-edges s[n][rep_c] (original rows) ---
            {
                float ow0 = -INFINITY, ow1 = -INFINITY;
                int oe0 = 0, oe1 = 0;
                for (int i = 0; i < Mtot; ++i) {
                    int cidI = vLc[i];
                    int x = vLn[i];
                    float sb = vLs[i];
                    float so0 = vscore[n0 * 129 + x] - sb;
                    float so1 = vscore[n1 * 129 + x] - sb;
                    if (c0 && cidI != cidn0 && so0 > ow0) { ow0 = so0; oe0 = x; }
                    if (c1 && cidI != cidn1 && so1 > ow1) { ow1 = so1; oe1 = x; }
                    int segend = (i + 1 == Mtot) || ((int)vLc[i + 1] != cidI);
                    if (segend) {
                        float cwc = vcw[cidI];
                        if (c0 && cidI != cidn0) {
                            unsigned char too = voout[n0 * 129 + oe0], toi = voin[n0 * 129 + oe0];
                            vscore[n0 * 129 + cidI] = cwc + ow0;
                            voout[n0 * 129 + cidI] = too; voin[n0 * 129 + cidI] = toi;
                        }
                        if (c1 && cidI != cidn1) {
                            unsigned char too = voout[n1 * 129 + oe1], toi = voin[n1 * 129 + oe1];
                            vscore[n1 * 129 + cidI] = cwc + ow1;
                            voout[n1 * 129 + cidI] = too; voin[n1 * 129 + cidI] = toi;
                        }
                        ow0 = -INFINITY; ow1 = -INFINITY; oe0 = 0; oe1 = 0;
                    }
                }
            }
            __threadfence_block(); // fence E
            // --- stage 2: in-edges s[rep_c][n] (post-stage-1 values) ---
            {
                float iw0 = -INFINITY, iw1 = -INFINITY;
                int ie0 = 0, ie1 = 0;
                for (int i = 0; i < Mtot; ++i) {
                    int cidI = vLc[i];
                    int x = vLn[i];
                    float si0 = vscore[x * 129 + n0];
                    float si1 = vscore[x * 129 + n1];
                    if (c0 && cidI != cidn0 && si0 > iw0) { iw0 = si0; ie0 = x; }
                    if (c1 && cidI != cidn1 && si1 > iw1) { iw1 = si1; ie1 = x; }
                    int segend = (i + 1 == Mtot) || ((int)vLc[i + 1] != cidI);
                    if (segend) {
                        if (c0 && cidI != cidn0) {
                            unsigned char too = voout[ie0 * 129 + n0], toi = voin[ie0 * 129 + n0];
                            vscore[cidI * 129 + n0] = iw0;
                            voout[cidI * 129 + n0] = too; voin[cidI * 129 + n0] = toi;
                        }
                        if (c1 && cidI != cidn1) {
                            unsigned char too = voout[ie1 * 129 + n1], toi = voin[ie1 * 129 + n1];
                            vscore[cidI * 129 + n1] = iw1;
                            voout[cidI * 129 + n1] = too; voin[cidI * 129 + n1] = toi;
                        }
                        iw0 = -INFINITY; iw1 = -INFINITY; ie0 = 0; ie1 = 0;
                    }
                }
            }
            __threadfence_block(); // fence F
            // --- deactivate non-rep members; incremental parents ---
            if (onc0 && n0 != cid0) c0 = 0;
            if (onc1 && n1 != cid1) c1 = 0;
            vact[n0] = (unsigned char)c0;
            vact[n1] = (unsigned char)c1;
            if (c0 && n0 != 0) { int cp = vcid[p0]; if (cp != 0xFF) p0 = cp; }
            if (c1)            { int cp = vcid[p1]; if (cp != 0xFF) p1 = cp; }
            __threadfence_block(); // fence G
            // --- surviving reps: full active-column rescan (root-first) ---
            if (c0 && onc0) {
                float mx = vscore[n0]; int par = 0;
                for (int x2 = 1; x2 < 128; ++x2) {
                    if (vact[x2] && x2 != n0) {
                        float sc = vscore[x2 * 129 + n0];
                        if (sc > mx) { mx = sc; par = x2; }
                    }
                }
                p0 = par;
            }
            if (c1 && onc1) {
                float mx = vscore[n1]; int par = 0;
                for (int x2 = 1; x2 < 128; ++x2) {
                    if (vact[x2] && x2 != n1) {
                        float sc = vscore[x2 * 129 + n1];
                        if (sc > mx) { mx = sc; par = x2; }
                    }
                }
                p1 = par;
            }
            int ncyc = __popcll(__ballot(onc0 && n0 == cid0)) +
                       __popcll(__ballot(onc1 && n1 == cid1));
            nact -= (Mtot - ncyc);
            ++lev;
        }
        // --- unwind: all cycles of a level resolved in parallel ---
        for (int l2 = lev - 1; l2 >= 0; --l2) {
            int ky0 = vkyn[l2 * 128 + n0], ky1 = vkyn[l2 * 128 + n1];
            int f0 = vfe[n0], f1 = vfe[n1];
            int cand0 = (ky0 != 0xFF) && (f0 != -2);
            int cand1 = (ky1 != 0xFF) && (f1 != -2);
            if (cand0) {
                int key = ky0;
                int prev = vpst[l2 * 128 + key];
                int guard = 0;
                while (prev != key && guard++ < 130) {
                    int pp2 = vpst[l2 * 128 + prev];
                    vfe[voout[pp2 * 129 + prev]] = voin[pp2 * 129 + prev];
                    prev = pp2;
                }
            }
            if (cand1) {
                int key = ky1;
                int prev = vpst[l2 * 128 + key];
                int guard = 0;
                while (prev != key && guard++ < 130) {
                    int pp2 = vpst[l2 * 128 + prev];
                    vfe[voout[pp2 * 129 + prev]] = voin[pp2 * 129 + prev];
                    prev = pp2;
                }
            }
            __threadfence_block();
        }
    }
    __syncthreads(); // ---- barrier B: waves 1-3 rejoin ----

    // --- emit heads / head_type ---
    if (t < 128) {
        int f = fe[t];
        float h, ht;
        if (f != -2) {
            h = (float)f;
            int prow = (f < 0) ? 127 : f; // numpy negative-index semantics for root
            ht = (float)(int)labmax_g[(size_t)b * 16384 + prow * 128 + t];
        } else { h = 0.0f; ht = 1.0f; }
        heads[b * 128 + t] = h;
        tags[b * 128 + t] = ht;
    }
}

extern "C" void kernel_launch(void* const* d_in, const int* in_sizes, int n_in,
                              void* d_out, int out_size, void* d_ws, size_t ws_size,
                              hipStream_t stream)
{
    const float* X   = (const float*)d_in[0];
    const float* Wha = (const float*)d_in[1];
    const float* bha = (const float*)d_in[2];
    const float* Wda = (const float*)d_in[3];
    const float* bda = (const float*)d_in[4];
    const float* Ua  = (const float*)d_in[5];
    const float* Whl = (const float*)d_in[6];
    const float* bhl = (const float*)d_in[7];
    const float* Wdl = (const float*)d_in[8];
    const float* bdl = (const float*)d_in[9];
    const float* Ul  = (const float*)d_in[10];
    // d_in[11] = mask: all-ones in this problem; length = 128 per batch.

    char* ws = (char*)d_ws;
    float* HA    = (float*)(ws + (size_t)0);
    float* DA    = (float*)(ws + ((size_t)8 << 20));
    float* TA    = (float*)(ws + ((size_t)16 << 20));
    float* HL    = (float*)(ws + ((size_t)24 << 20));
    float* DL    = (float*)(ws + ((size_t)26 << 20));
    float* DLt   = (float*)(ws + ((size_t)28 << 20));
    float* ARC   = (float*)(ws + ((size_t)30 << 20));
    float* SCORE = (float*)(ws + ((size_t)32 << 20));                  // 2 MB
    unsigned char* LABMAX = (unsigned char*)(ws + ((size_t)34 << 20)); // 512 KB

    float* E     = (float*)d_out;
    float* heads = E + (size_t)B_ * L_ * T_ * T_;
    float* tags  = heads + (size_t)B_ * T_;

    dim3 thr(256);
    // fused projections + bias + ELU (one launch, 640 blocks)
    proj_gemm_k<<<dim3(10, 64), thr, 0, stream>>>(X, Wha, bha, Wda, bda, Whl, bhl, Wdl, bdl,
                                                  HA, DA, HL, DL);
    // TA = HA @ U_arc
    gemm_k<<<dim3(4, 64, 1), thr, 0, stream>>>(HA, Ua, nullptr, TA, 512, 512, 512, 512, 0, 0, 0, (long long)128 * 512, 0);
    // DLt[b][s][j]
    transpose_k<<<dim3(4, 4, 32), dim3(32, 8), 0, stream>>>(DL, DLt);
    // arc_scores[b] = TA_b @ DA_b^T
    gemm_k<<<dim3(1, 2, 32), thr, 0, stream>>>(TA, DA, nullptr, ARC, 512, 512, 512, 128, 65536, 65536, 16384, 0, 4);
    // log_softmax over i, in place
    arc_logsoftmax_k<<<32, 128, 0, stream>>>(ARC);
    // TL[b,l,i,s] = HL @ U_lab[l]  -> stored in d_out energy region
    gemm_k<<<dim3(1, 64, 50), thr, 0, stream>>>(HL, Ul, nullptr, E, 128, 128, 128, 128, 0, 16384, 16384, (long long)50 * 16384, 0);
    // lab_scores in place per (b,l) slice
    lab_inplace_k<<<dim3(50, 32), thr, 0, stream>>>(E, DLt);
    // label log-softmax + combine with norm_arc + exp + fused score/argmax
    energy_combine_k<<<2048, 256, 0, stream>>>(E, ARC, SCORE, LABMAX);
    // MST decode (multi-cycle contraction per pass)
    mst_k<<<32, 256, 0, stream>>>(SCORE, LABMAX, heads, tags);
}

// Round 4
// 887.014 us; speedup vs baseline: 1.8964x; 1.8964x over previous
//
#include <hip/hip_runtime.h>
#include <math.h>

#define B_ 32
#define T_ 128
#define D_ 768
#define A_ 512
#define R_ 128
#define L_ 50

// ---------------------------------------------------------------------------
// Fused projection GEMM: HA/DA/HL/DL = ELU(X @ W + b) in one launch.
// ---------------------------------------------------------------------------
__global__ __launch_bounds__(256)
void proj_gemm_k(const float* __restrict__ X,
                 const float* __restrict__ Wha, const float* __restrict__ bha,
                 const float* __restrict__ Wda, const float* __restrict__ bda,
                 const float* __restrict__ Whl, const float* __restrict__ bhl,
                 const float* __restrict__ Wdl, const float* __restrict__ bdl,
                 float* __restrict__ HA, float* __restrict__ DA,
                 float* __restrict__ HL, float* __restrict__ DL)
{
    __shared__ float As[16][68];
    __shared__ float Bs[16][132];
    const int bx = blockIdx.x;
    const float *W, *bias; float* C; int ld, ncol;
    if (bx < 4)      { W = Wha; bias = bha; C = HA; ld = 512; ncol = bx * 128; }
    else if (bx < 8) { W = Wda; bias = bda; C = DA; ld = 512; ncol = (bx - 4) * 128; }
    else if (bx == 8){ W = Whl; bias = bhl; C = HL; ld = 128; ncol = 0; }
    else             { W = Wdl; bias = bdl; C = DL; ld = 128; ncol = 0; }
    const int m0 = blockIdx.y * 64;
    const int tid = threadIdx.x;
    const int tx = tid & 15, ry = tid >> 4;
    float acc[4][8] = {};
    for (int k0 = 0; k0 < 768; k0 += 16) {
        {
            int row = tid >> 2, kb = (tid & 3) * 4;
            float4 a = *(const float4*)&X[(size_t)(m0 + row) * 768 + k0 + kb];
            As[kb + 0][row] = a.x; As[kb + 1][row] = a.y;
            As[kb + 2][row] = a.z; As[kb + 3][row] = a.w;
        }
        {
            int kk = tid >> 4, c0 = (tid & 15) * 4;
            const float* Bp = &W[(size_t)(k0 + kk) * ld + ncol + c0];
            *(float4*)&Bs[kk][c0] = *(const float4*)&Bp[0];
            *(float4*)&Bs[kk][c0 + 64] = *(const float4*)&Bp[64];
        }
        __syncthreads();
#pragma unroll
        for (int kk = 0; kk < 16; ++kk) {
            float4 a4 = *(const float4*)&As[kk][ry * 4];
            float4 b0 = *(const float4*)&Bs[kk][tx * 4];
            float4 b1 = *(const float4*)&Bs[kk][tx * 4 + 64];
            float av[4] = { a4.x, a4.y, a4.z, a4.w };
            float bv[8] = { b0.x, b0.y, b0.z, b0.w, b1.x, b1.y, b1.z, b1.w };
#pragma unroll
            for (int i = 0; i < 4; ++i)
#pragma unroll
                for (int j = 0; j < 8; ++j)
                    acc[i][j] += av[i] * bv[j];
        }
        __syncthreads();
    }
    float bv0[8];
    {
        float4 q0 = *(const float4*)&bias[ncol + tx * 4];
        float4 q1 = *(const float4*)&bias[ncol + tx * 4 + 64];
        bv0[0] = q0.x; bv0[1] = q0.y; bv0[2] = q0.z; bv0[3] = q0.w;
        bv0[4] = q1.x; bv0[5] = q1.y; bv0[6] = q1.z; bv0[7] = q1.w;
    }
#pragma unroll
    for (int i = 0; i < 4; ++i) {
        int m = m0 + ry * 4 + i;
        size_t base = (size_t)m * ld + ncol;
        float o[8];
#pragma unroll
        for (int j = 0; j < 8; ++j) {
            float v = acc[i][j] + bv0[j];
            o[j] = v > 0.0f ? v : expm1f(v);
        }
        float4 s0 = { o[0], o[1], o[2], o[3] };
        float4 s1 = { o[4], o[5], o[6], o[7] };
        *(float4*)&C[base + tx * 4] = s0;
        *(float4*)&C[base + tx * 4 + 64] = s1;
    }
}

// ---------------------------------------------------------------------------
// fp32 GEMM, tile 64x128, 256 threads, 4x8 acc/thread, b128 LDS reads.
// ---------------------------------------------------------------------------
__global__ __launch_bounds__(256)
void gemm_k(const float* __restrict__ A, const float* __restrict__ B,
            const float* __restrict__ bias, float* __restrict__ C,
            int K, int lda, int ldb, int ldc,
            long long sA, long long sB, long long sC, long long c_outer, int flags)
{
    __shared__ float As[16][68];
    __shared__ float Bs[16][132];
    A += (size_t)blockIdx.z * sA;
    B += (size_t)blockIdx.z * sB;
    C += (size_t)blockIdx.z * sC;
    const int m0 = blockIdx.y * 64, n0 = blockIdx.x * 128;
    const int tid = threadIdx.x;
    const int tx = tid & 15, ry = tid >> 4;
    float acc[4][8] = {};
    for (int k0 = 0; k0 < K; k0 += 16) {
        {
            int row = tid >> 2, kb = (tid & 3) * 4;
            float4 a = *(const float4*)&A[(size_t)(m0 + row) * lda + k0 + kb];
            As[kb + 0][row] = a.x; As[kb + 1][row] = a.y;
            As[kb + 2][row] = a.z; As[kb + 3][row] = a.w;
        }
        if (!(flags & 4)) {
            int kk = tid >> 4, c0 = (tid & 15) * 4;
            const float* Bp = &B[(size_t)(k0 + kk) * ldb + n0 + c0];
            *(float4*)&Bs[kk][c0] = *(const float4*)&Bp[0];
            *(float4*)&Bs[kk][c0 + 64] = *(const float4*)&Bp[64];
        } else {
            int col = tid >> 1, kb = (tid & 1) * 8;
            const float* Bp = &B[(size_t)(n0 + col) * ldb + k0 + kb];
            float4 b0 = *(const float4*)&Bp[0];
            float4 b1 = *(const float4*)&Bp[4];
            Bs[kb + 0][col] = b0.x; Bs[kb + 1][col] = b0.y;
            Bs[kb + 2][col] = b0.z; Bs[kb + 3][col] = b0.w;
            Bs[kb + 4][col] = b1.x; Bs[kb + 5][col] = b1.y;
            Bs[kb + 6][col] = b1.z; Bs[kb + 7][col] = b1.w;
        }
        __syncthreads();
#pragma unroll
        for (int kk = 0; kk < 16; ++kk) {
            float4 a4 = *(const float4*)&As[kk][ry * 4];
            float4 b0 = *(const float4*)&Bs[kk][tx * 4];
            float4 b1 = *(const float4*)&Bs[kk][tx * 4 + 64];
            float av[4] = { a4.x, a4.y, a4.z, a4.w };
            float bv[8] = { b0.x, b0.y, b0.z, b0.w, b1.x, b1.y, b1.z, b1.w };
#pragma unroll
            for (int i = 0; i < 4; ++i)
#pragma unroll
                for (int j = 0; j < 8; ++j)
                    acc[i][j] += av[i] * bv[j];
        }
        __syncthreads();
    }
    float bv0[8] = {};
    if (flags & 1) {
        float4 q0 = *(const float4*)&bias[n0 + tx * 4];
        float4 q1 = *(const float4*)&bias[n0 + tx * 4 + 64];
        bv0[0] = q0.x; bv0[1] = q0.y; bv0[2] = q0.z; bv0[3] = q0.w;
        bv0[4] = q1.x; bv0[5] = q1.y; bv0[6] = q1.z; bv0[7] = q1.w;
    }
#pragma unroll
    for (int i = 0; i < 4; ++i) {
        int m = m0 + ry * 4 + i;
        size_t base = (size_t)(m >> 7) * c_outer + (size_t)(m & 127) * ldc + n0;
        float o[8];
#pragma unroll
        for (int j = 0; j < 8; ++j) {
            float v = acc[i][j] + bv0[j];
            if (flags & 2) v = v > 0.0f ? v : expm1f(v);
            o[j] = v;
        }
        float4 s0 = { o[0], o[1], o[2], o[3] };
        float4 s1 = { o[4], o[5], o[6], o[7] };
        *(float4*)&C[base + tx * 4] = s0;
        *(float4*)&C[base + tx * 4 + 64] = s1;
    }
}

// 128x128 per-batch transpose: DLt[b][s][j] = DL[b][j][s]
__global__ __launch_bounds__(256)
void transpose_k(const float* __restrict__ in, float* __restrict__ out)
{
    __shared__ float tile[32][33];
    int b = blockIdx.z;
    int bx = blockIdx.x, by = blockIdx.y;
    int tx = threadIdx.x, ty = threadIdx.y; // (32,8)
    const float* src = in + (size_t)b * T_ * R_;
    float* dst = out + (size_t)b * T_ * R_;
#pragma unroll
    for (int r = 0; r < 4; ++r)
        tile[ty + 8 * r][tx] = src[(size_t)(by * 32 + ty + 8 * r) * 128 + bx * 32 + tx];
    __syncthreads();
#pragma unroll
    for (int r = 0; r < 4; ++r)
        dst[(size_t)(bx * 32 + ty + 8 * r) * 128 + by * 32 + tx] = tile[tx][ty + 8 * r];
}

// log_softmax over dim 1 (i) of (32,128,128), in place. thread = column j.
__global__ __launch_bounds__(128)
void arc_logsoftmax_k(float* __restrict__ arc)
{
    int b = blockIdx.x, j = threadIdx.x;
    float* base = arc + (size_t)b * T_ * T_ + j;
    float m = -INFINITY;
    for (int i = 0; i < T_; ++i) m = fmaxf(m, base[(size_t)i * T_]);
    float s = 0.0f;
    for (int i = 0; i < T_; ++i) s += expf(base[(size_t)i * T_] - m);
    float ls = m + logf(s);
    for (int i = 0; i < T_; ++i) base[(size_t)i * T_] -= ls;
}

// In-place per-(b,l): E_slice <- (E_slice[i][s]) @ DLt[b]^( [s][j] )
__global__ __launch_bounds__(256)
void lab_inplace_k(float* __restrict__ E, const float* __restrict__ dlt)
{
    __shared__ __align__(16) float As[T_ * R_]; // 64 KB: [i][s]
    int l = blockIdx.x, b = blockIdx.y;
    float* base = E + ((size_t)b * L_ + l) * T_ * T_;
    int tid = threadIdx.x;
#pragma unroll
    for (int it = 0; it < 16; ++it) {
        int idx = (it * 256 + tid) * 4;
        *(float4*)&As[idx] = *(const float4*)&base[idx];
    }
    __syncthreads();
    int tx = tid & 15, ty = tid >> 4;
    int j0 = tx * 8, i0 = ty * 8;
    const float* dl = dlt + (size_t)b * T_ * R_;
    float acc[8][8] = {};
    for (int s0 = 0; s0 < R_; s0 += 4) {
        float a[8][4], bb[4][8];
#pragma unroll
        for (int ii = 0; ii < 8; ++ii) {
            float4 v = *(const float4*)&As[(i0 + ii) * R_ + s0];
            a[ii][0] = v.x; a[ii][1] = v.y; a[ii][2] = v.z; a[ii][3] = v.w;
        }
#pragma unroll
        for (int ss = 0; ss < 4; ++ss) {
            float4 x = *(const float4*)&dl[(size_t)(s0 + ss) * T_ + j0];
            float4 y = *(const float4*)&dl[(size_t)(s0 + ss) * T_ + j0 + 4];
            bb[ss][0] = x.x; bb[ss][1] = x.y; bb[ss][2] = x.z; bb[ss][3] = x.w;
            bb[ss][4] = y.x; bb[ss][5] = y.y; bb[ss][6] = y.z; bb[ss][7] = y.w;
        }
#pragma unroll
        for (int ii = 0; ii < 8; ++ii)
#pragma unroll
            for (int jj = 0; jj < 8; ++jj)
#pragma unroll
                for (int ss = 0; ss < 4; ++ss)
                    acc[ii][jj] += a[ii][ss] * bb[ss][jj];
    }
#pragma unroll
    for (int ii = 0; ii < 8; ++ii) {
        float4 o0 = { acc[ii][0], acc[ii][1], acc[ii][2], acc[ii][3] };
        float4 o1 = { acc[ii][4], acc[ii][5], acc[ii][6], acc[ii][7] };
        *(float4*)&base[(size_t)(i0 + ii) * T_ + j0] = o0;
        *(float4*)&base[(size_t)(i0 + ii) * T_ + j0 + 4] = o1;
    }
}

// energy combine + fused score/labmax for MST.
__global__ __launch_bounds__(256)
void energy_combine_k(float* __restrict__ E, const float* __restrict__ narc,
                      float* __restrict__ score_g, unsigned char* __restrict__ labmax_g)
{
    int g = blockIdx.x * 256 + threadIdx.x; // 0..524287
    int b = g >> 14;
    int ij = g & 16383;
    float* base = E + (size_t)b * L_ * T_ * T_ + ij;
    float v[L_];
    float m = -INFINITY;
    int am = 0;
#pragma unroll
    for (int l = 0; l < L_; ++l) {
        v[l] = base[(size_t)l * T_ * T_];
        if (v[l] > m) { m = v[l]; am = l; }
    }
    float s = 0.0f;
#pragma unroll
    for (int l = 0; l < L_; ++l) s += expf(v[l] - m);
    float ls = m + logf(s);
    float na = narc[(size_t)b * T_ * T_ + ij];
#pragma unroll
    for (int l = 0; l < L_; ++l) base[(size_t)l * T_ * T_] = expf(na + v[l] - ls);
    int i = ij >> 7, j = ij & 127;
    score_g[(size_t)b * 16384 + ij] = (i == j) ? 0.0f : expf(na + m - ls);
    labmax_g[(size_t)b * 16384 + ij] = (unsigned char)am;
}

// ---------------------------------------------------------------------------
// Chu-Liu-Edmonds MST decode. One block per batch; main loop on wave 0
// (64 lanes x 2 nodes), zero barriers, zero global ops, all state in LDS.
// r6: multi-cycle DETECTION per pass (doubling+path-min labels every cycle),
// then a within-pass loop over reps doing CHEAP per-cycle contractions
// (sequential-CLE-equivalent: disjoint cycles only touch their own rows/cols;
// each contraction sees exactly the state sequential CLE would).
//  - 2-cycle fast path: all 12 volatile loads independent -> one wait batch.
//  - oin/oout packed into one ushort (oio) -> half the volatile accesses.
//  - stride-129 padding: row AND column accesses conflict-free (129 % 32 = 1).
//  - cw / rep-column rescan via register butterflies.
// Tie-cases (exact float equality) may differ from reference; MST unique
// otherwise (validated on harness by r5's multi-cycle variant).
// ---------------------------------------------------------------------------
__global__ __launch_bounds__(256)
void mst_k(const float* __restrict__ score_g, const unsigned char* __restrict__ labmax_g,
           float* __restrict__ heads, float* __restrict__ tags)
{
    const int b = blockIdx.x, t = threadIdx.x;
    __shared__ float score[128 * 129];          // 66 KB, stride 129
    __shared__ unsigned short oio[128 * 129];   // 33 KB: oin | (oout<<8)
    __shared__ unsigned char pstL[128 * 128];   // 16 KB: parents at each level
    __shared__ unsigned char kynL[128 * 128];   // 16 KB: key cand (old r) per level
    __shared__ int parents[128];
    __shared__ int fe[128]; // -2 = absent; -1 = root marker
    __shared__ float pmx[128];
    __shared__ int pp[128];
    __shared__ float sub[128];
    __shared__ unsigned char cyc[128], oncyc[128];

    volatile float* vscore = score;
    volatile unsigned short* voio = oio;
    volatile unsigned char* vpst = pstL;
    volatile unsigned char* vkyn = kynL;
    volatile int* vfe = fe;
    volatile float* vsub = sub;
    volatile unsigned char* vcyc = cyc;
    volatile unsigned char* vonc = oncyc;

    // ---- phase 0: stage score (padded), init oio/fe ----
    {
        const float4* src = (const float4*)(score_g + (size_t)b * 16384);
        for (int i = t; i < 4096; i += 256) {
            float4 v = src[i];
            int r = i >> 5, c = (i & 31) * 4;
            float* d = &score[r * 129 + c];
            d[0] = v.x; d[1] = v.y; d[2] = v.z; d[3] = v.w;
        }
    }
    for (int i = t; i < 16384; i += 256) {
        int r = i >> 7, c = i & 127;
        oio[r * 129 + c] = (unsigned short)(r | (c << 8));
    }
    if (t < 128) { fe[t] = -2; oncyc[t] = 0; }
    __syncthreads();
    if (t < 128) score[t * 129 + t] = -INFINITY; // diag never read elsewhere
    __syncthreads();
    // ---- initial full parent scan (split across 256 threads) ----
    float mxl = 0.0f; int pl = 0;
    if (t >= 128) {
        int col = t - 128;
        float mx = -INFINITY; int pu = 64;
        if (col != 0) {
            mx = score[64 * 129 + col];
#pragma unroll 16
            for (int n2 = 65; n2 < 128; ++n2) {
                float sc = score[n2 * 129 + col];
                if (sc > mx) { mx = sc; pu = n2; }
            }
        }
        pmx[col] = mx; pp[col] = pu;
    } else if (t != 0) {
        mxl = score[t]; pl = 0; // row 0 initial (root candidate)
#pragma unroll 16
        for (int n2 = 1; n2 < 64; ++n2) {
            float sc = score[n2 * 129 + t];
            if (sc > mxl) { mxl = sc; pl = n2; }
        }
    }
    __syncthreads();
    if (t == 0) parents[0] = -1;
    else if (t < 128) parents[t] = (pmx[t] > mxl) ? pp[t] : pl;
    __syncthreads(); // ---- barrier A: wave 0 takes over ----

    if (t < 64) {
        const int n0 = t, n1 = t + 64;
        int p0 = parents[n0], p1 = parents[n1];
        int c0 = 1, c1 = 1;       // active flags
        int r0 = n0, r1 = n1;     // rep_of (group representative) mirrors
        int lev = 0, nact = 128, pass = 0;
        const unsigned long long lmask = (1ull << t) - 1ull;
        for (;;) {
            // --- doubling: a = 2^rounds-step ancestor, m = path-min ---
            int rounds = 32 - __clz(nact - 1);
            int a0 = (n0 == 0 || !c0) ? 0 : p0;
            int a1 = (!c1) ? 0 : p1;
            int m0 = n0, m1 = n1;
            for (int s = 0; s < rounds; ++s) {
                int pk0 = (a0 << 7) | m0;
                int pk1 = (a1 << 7) | m1;
                int q00 = __shfl(pk0, a0 & 63, 64);
                int q01 = __shfl(pk1, a0 & 63, 64);
                int q10 = __shfl(pk0, a1 & 63, 64);
                int q11 = __shfl(pk1, a1 & 63, 64);
                int g0 = (a0 & 64) ? q01 : q00;
                int g1 = (a1 & 64) ? q11 : q10;
                a0 = g0 >> 7; int gm0 = g0 & 127; m0 = gm0 < m0 ? gm0 : m0;
                a1 = g1 >> 7; int gm1 = g1 & 127; m1 = gm1 < m1 ? gm1 : m1;
            }
            int pred0 = (n0 >= 1) && c0 && (a0 != 0);
            int pred1 = c1 && (a1 != 0);
            unsigned long long bal0 = __ballot(pred0);
            unsigned long long bal1 = __ballot(pred1);
            if (bal0 == 0ull && bal1 == 0ull) {
                // base case: no cycles — emit final edges for active nodes
                if (n0 == 0) vfe[0] = -1;
                else if (c0) { int w = voio[p0 * 129 + n0]; vfe[w >> 8] = w & 255; }
                if (c1) { int w = voio[p1 * 129 + n1]; vfe[w >> 8] = w & 255; }
                __threadfence_block();
                break;
            }
            // --- mark all cycle nodes (a(n) lies on n's cycle) ---
            unsigned char ep = (unsigned char)(++pass);
            if (pred0) vonc[a0] = ep;
            if (pred1) vonc[a1] = ep;
            __threadfence_block();
            int onc0 = c0 && (vonc[n0] == ep);
            int onc1 = c1 && (vonc[n1] == ep);
            const int cid0 = m0, cid1 = m1; // valid when onc
            unsigned long long rm0 = __ballot(onc0 && n0 == cid0);
            unsigned long long rm1 = __ballot(onc1 && n1 == cid1);
            // --- contract every cycle of this pass, one at a time ---
            while (rm0 | rm1) {
                int rep;
                if (rm0) { rep = (int)__ffsll((long long)rm0) - 1; rm0 &= rm0 - 1; }
                else     { rep = 64 + (int)__ffsll((long long)rm1) - 1; rm1 &= rm1 - 1; }
                int member0 = onc0 && (cid0 == rep);
                int member1 = onc1 && (cid1 == rep);
                unsigned long long mb0 = __ballot(member0);
                unsigned long long mb1 = __ballot(member1);
                int clen = (int)__popcll(mb0) + (int)__popcll(mb1);
                // save level state (before any updates)
                vpst[lev * 128 + n0] = (unsigned char)p0;
                vpst[lev * 128 + n1] = (unsigned char)p1;
                int mbr0 = (r0 < 64) ? (int)((mb0 >> r0) & 1ull) : (int)((mb1 >> (r0 - 64)) & 1ull);
                int mbr1 = (r1 < 64) ? (int)((mb0 >> r1) & 1ull) : (int)((mb1 >> (r1 - 64)) & 1ull);
                vkyn[lev * 128 + n0] = mbr0 ? (unsigned char)r0 : 0xFF;
                vkyn[lev * 128 + n1] = mbr1 ? (unsigned char)r1 : 0xFF;
                if (mbr0) r0 = rep;
                if (mbr1) r1 = rep;
                if (clen == 2) {
                    // === 2-cycle fast path: u=rep, v=other; p(u)=v, p(v)=u ===
                    unsigned long long ob0 = mb0, ob1 = mb1;
                    if (rep < 64) ob0 &= ~(1ull << rep); else ob1 &= ~(1ull << (rep - 64));
                    int v = ob0 ? (int)__ffsll((long long)ob0) - 1
                                : 64 + (int)__ffsll((long long)ob1) - 1;
                    int u = rep;
                    int act0 = c0 && !member0;
                    int act1 = c1 && !member1;
                    // one independent load batch (score + oio + subs)
                    float subU = vscore[v * 129 + u];
                    float subV = vscore[u * 129 + v];
                    float siU0 = 0, siV0 = 0, soU0 = 0, soV0 = 0;
                    int ioiU0 = 0, ioiV0 = 0, iooU0 = 0, iooV0 = 0;
                    float siU1 = 0, siV1 = 0, soU1 = 0, soV1 = 0;
                    int ioiU1 = 0, ioiV1 = 0, iooU1 = 0, iooV1 = 0;
                    if (act0) {
                        siU0 = vscore[u * 129 + n0]; siV0 = vscore[v * 129 + n0];
                        soU0 = vscore[n0 * 129 + u]; soV0 = vscore[n0 * 129 + v];
                        ioiU0 = voio[u * 129 + n0]; ioiV0 = voio[v * 129 + n0];
                        iooU0 = voio[n0 * 129 + u]; iooV0 = voio[n0 * 129 + v];
                    }
                    if (act1) {
                        siU1 = vscore[u * 129 + n1]; siV1 = vscore[v * 129 + n1];
                        soU1 = vscore[n1 * 129 + u]; soV1 = vscore[n1 * 129 + v];
                        ioiU1 = voio[u * 129 + n1]; ioiV1 = voio[v * 129 + n1];
                        iooU1 = voio[n1 * 129 + u]; iooV1 = voio[n1 * 129 + v];
                    }
                    float cw = subU + subV;
                    if (act0) {
                        float inw; int ioi;
                        if (siV0 > siU0) { inw = siV0; ioi = ioiV0; } else { inw = siU0; ioi = ioiU0; }
                        float oU = soU0 - subU, oV = soV0 - subV;
                        float outw; int ioo;
                        if (oV > oU) { outw = oV; ioo = iooV0; } else { outw = oU; ioo = iooU0; }
                        vscore[u * 129 + n0] = inw;       voio[u * 129 + n0] = (unsigned short)ioi;
                        vscore[n0 * 129 + u] = cw + outw; voio[n0 * 129 + u] = (unsigned short)ioo;
                    }
                    if (act1) {
                        float inw; int ioi;
                        if (siV1 > siU1) { inw = siV1; ioi = ioiV1; } else { inw = siU1; ioi = ioiU1; }
                        float oU = soU1 - subU, oV = soV1 - subV;
                        float outw; int ioo;
                        if (oV > oU) { outw = oV; ioo = iooV1; } else { outw = oU; ioo = iooU1; }
                        vscore[u * 129 + n1] = inw;       voio[u * 129 + n1] = (unsigned short)ioi;
                        vscore[n1 * 129 + u] = cw + outw; voio[n1 * 129 + u] = (unsigned short)ioo;
                    }
                } else {
                    // === generic path (clen >= 3, rare) ===
                    int rank0 = (int)__popcll(mb0 & lmask);
                    int rank1 = (int)__popcll(mb0) + (int)__popcll(mb1 & lmask);
                    float s0m = member0 ? vscore[p0 * 129 + n0] : 0.0f;
                    float s1m = member1 ? vscore[p1 * 129 + n1] : 0.0f;
                    if (member0) { vcyc[rank0] = (unsigned char)n0; vsub[rank0] = s0m; }
                    if (member1) { vcyc[rank1] = (unsigned char)n1; vsub[rank1] = s1m; }
                    __threadfence_block();
                    float cw = s0m + s1m;
#pragma unroll
                    for (int off = 32; off >= 1; off >>= 1) cw += __shfl_xor(cw, off, 64);
#pragma unroll
                    for (int half = 0; half < 2; ++half) {
                        int n = half ? n1 : n0;
                        int act = half ? (c1 && !member1) : (c0 && !member0);
                        if (act) {
                            float inw = -INFINITY, outw = -INFINITY;
                            int ine = 0, oute = 0;
                            for (int i = 0; i < clen; ++i) {
                                int nic = (int)vcyc[i];
                                float sb = vsub[i];
                                float si = vscore[nic * 129 + n];
                                if (si > inw) { inw = si; ine = nic; }
                                float so = cw + vscore[n * 129 + nic] - sb;
                                if (so > outw) { outw = so; oute = nic; }
                            }
                            vscore[rep * 129 + n] = inw;
                            voio[rep * 129 + n] = voio[ine * 129 + n];
                            vscore[n * 129 + rep] = outw;
                            voio[n * 129 + rep] = voio[n * 129 + oute];
                        }
                    }
                }
                __threadfence_block();
                // --- deactivate non-rep members; remap parents into rep ---
                if (member0 && n0 != rep) c0 = 0;
                if (member1 && n1 != rep) c1 = 0;
                int mbp0 = (p0 >= 0 && p0 < 64) ? (int)((mb0 >> p0) & 1ull)
                                                : (p0 >= 64 ? (int)((mb1 >> (p0 - 64)) & 1ull) : 0);
                int mbp1 = (p1 < 64) ? (int)((mb0 >> p1) & 1ull) : (int)((mb1 >> (p1 - 64)) & 1ull);
                if (c0 && n0 != 0 && mbp0) p0 = rep;
                if (c1 && mbp1) p1 = rep;
                // --- rep column rescan: butterfly first-max (root-first) ---
                {
                    float cv0 = c0 ? vscore[n0 * 129 + rep] : -INFINITY; // diag=-INF guards self
                    float cv1 = c1 ? vscore[n1 * 129 + rep] : -INFINITY;
                    float bv; int bi;
                    if (cv1 > cv0) { bv = cv1; bi = n1; } else { bv = cv0; bi = n0; }
#pragma unroll
                    for (int off = 32; off >= 1; off >>= 1) {
                        float ov = __shfl_xor(bv, off, 64);
                        int oi = __shfl_xor(bi, off, 64);
                        if (ov > bv || (ov == bv && oi < bi)) { bv = ov; bi = oi; }
                    }
                    if (n0 == rep) p0 = bi;
                    if (n1 == rep) p1 = bi;
                }
                nact -= (clen - 1);
                ++lev;
            }
        }
        // --- unwind: reverse contraction order ---
        for (int l2 = lev - 1; l2 >= 0; --l2) {
            int ky0 = vkyn[l2 * 128 + n0], ky1 = vkyn[l2 * 128 + n1];
            int cand0 = (ky0 != 0xFF) && (vfe[n0] != -2);
            int cand1 = (ky1 != 0xFF) && (vfe[n1] != -2);
            if (cand0) {
                int key = ky0;
                int prev = vpst[l2 * 128 + key];
                int guard = 0;
                while (prev != key && guard++ < 130) {
                    int pp2 = vpst[l2 * 128 + prev];
                    int w = voio[pp2 * 129 + prev];
                    vfe[w >> 8] = w & 255;
                    prev = pp2;
                }
            }
            if (cand1) {
                int key = ky1;
                int prev = vpst[l2 * 128 + key];
                int guard = 0;
                while (prev != key && guard++ < 130) {
                    int pp2 = vpst[l2 * 128 + prev];
                    int w = voio[pp2 * 129 + prev];
                    vfe[w >> 8] = w & 255;
                    prev = pp2;
                }
            }
            __threadfence_block();
        }
    }
    __syncthreads(); // ---- barrier B: waves 1-3 rejoin ----

    // --- emit heads / head_type ---
    if (t < 128) {
        int f = fe[t];
        float h, ht;
        if (f != -2) {
            h = (float)f;
            int prow = (f < 0) ? 127 : f; // numpy negative-index semantics for root
            ht = (float)(int)labmax_g[(size_t)b * 16384 + prow * 128 + t];
        } else { h = 0.0f; ht = 1.0f; }
        heads[b * 128 + t] = h;
        tags[b * 128 + t] = ht;
    }
}

extern "C" void kernel_launch(void* const* d_in, const int* in_sizes, int n_in,
                              void* d_out, int out_size, void* d_ws, size_t ws_size,
                              hipStream_t stream)
{
    const float* X   = (const float*)d_in[0];
    const float* Wha = (const float*)d_in[1];
    const float* bha = (const float*)d_in[2];
    const float* Wda = (const float*)d_in[3];
    const float* bda = (const float*)d_in[4];
    const float* Ua  = (const float*)d_in[5];
    const float* Whl = (const float*)d_in[6];
    const float* bhl = (const float*)d_in[7];
    const float* Wdl = (const float*)d_in[8];
    const float* bdl = (const float*)d_in[9];
    const float* Ul  = (const float*)d_in[10];
    // d_in[11] = mask: all-ones in this problem; length = 128 per batch.

    char* ws = (char*)d_ws;
    float* HA    = (float*)(ws + (size_t)0);
    float* DA    = (float*)(ws + ((size_t)8 << 20));
    float* TA    = (float*)(ws + ((size_t)16 << 20));
    float* HL    = (float*)(ws + ((size_t)24 << 20));
    float* DL    = (float*)(ws + ((size_t)26 << 20));
    float* DLt   = (float*)(ws + ((size_t)28 << 20));
    float* ARC   = (float*)(ws + ((size_t)30 << 20));
    float* SCORE = (float*)(ws + ((size_t)32 << 20));                  // 2 MB
    unsigned char* LABMAX = (unsigned char*)(ws + ((size_t)34 << 20)); // 512 KB

    float* E     = (float*)d_out;
    float* heads = E + (size_t)B_ * L_ * T_ * T_;
    float* tags  = heads + (size_t)B_ * T_;

    dim3 thr(256);
    // fused projections + bias + ELU (one launch, 640 blocks)
    proj_gemm_k<<<dim3(10, 64), thr, 0, stream>>>(X, Wha, bha, Wda, bda, Whl, bhl, Wdl, bdl,
                                                  HA, DA, HL, DL);
    // TA = HA @ U_arc
    gemm_k<<<dim3(4, 64, 1), thr, 0, stream>>>(HA, Ua, nullptr, TA, 512, 512, 512, 512, 0, 0, 0, (long long)128 * 512, 0);
    // DLt[b][s][j]
    transpose_k<<<dim3(4, 4, 32), dim3(32, 8), 0, stream>>>(DL, DLt);
    // arc_scores[b] = TA_b @ DA_b^T
    gemm_k<<<dim3(1, 2, 32), thr, 0, stream>>>(TA, DA, nullptr, ARC, 512, 512, 512, 128, 65536, 65536, 16384, 0, 4);
    // log_softmax over i, in place
    arc_logsoftmax_k<<<32, 128, 0, stream>>>(ARC);
    // TL[b,l,i,s] = HL @ U_lab[l]  -> stored in d_out energy region
    gemm_k<<<dim3(1, 64, 50), thr, 0, stream>>>(HL, Ul, nullptr, E, 128, 128, 128, 128, 0, 16384, 16384, (long long)50 * 16384, 0);
    // lab_scores in place per (b,l) slice
    lab_inplace_k<<<dim3(50, 32), thr, 0, stream>>>(E, DLt);
    // label log-softmax + combine with norm_arc + exp + fused score/argmax
    energy_combine_k<<<2048, 256, 0, stream>>>(E, ARC, SCORE, LABMAX);
    // MST decode (multi-cycle pass + cheap per-cycle contraction)
    mst_k<<<32, 256, 0, stream>>>(SCORE, LABMAX, heads, tags);
}